// Round 1
// baseline (1650.158 us; speedup 1.0000x reference)
//
#include <hip/hip_runtime.h>
#include <cstdint>
#include <cstddef>

typedef __attribute__((ext_vector_type(8))) __bf16 bf16x8;
typedef __attribute__((ext_vector_type(8))) unsigned short u16x8;
typedef __attribute__((ext_vector_type(4))) unsigned short u16x4;
typedef __attribute__((ext_vector_type(2))) unsigned short u16x2;
typedef __attribute__((ext_vector_type(4))) float f32x4;
typedef __attribute__((ext_vector_type(2))) float f32x2;

// ---- helpers -------------------------------------------------------------
__device__ __forceinline__ unsigned short f2bf(float f){
  unsigned int u = __float_as_uint(f);
  u += 0x7FFFu + ((u >> 16) & 1u);          // round to nearest even
  return (unsigned short)(u >> 16);
}
__device__ __forceinline__ float bf2f(unsigned short s){
  return __uint_as_float(((unsigned int)s) << 16);
}
__device__ __forceinline__ float sigm(float x){ return 1.f/(1.f + __expf(-x)); }
__device__ __forceinline__ float tanh_f(float x){ float e = __expf(2.f*x); return 1.f - 2.f/(e + 1.f); }
__device__ __forceinline__ f32x4 mfma16(u16x8 a, u16x8 b, f32x4 c){
  return __builtin_amdgcn_mfma_f32_16x16x32_bf16(
      __builtin_bit_cast(bf16x8, a), __builtin_bit_cast(bf16x8, b), c, 0, 0, 0);
}

// B=1024, T=128, F=128, H=256
// Sequential GEMM: S = h(1024x256) @ Wc(256x1024), Wc cols:
//   [0:256)   = Wih_h_r + Whh_r      (r gate, merged)
//   [256:512) = Wih_h_z + Whh_z      (z gate, merged)
//   [512:768) = Wih_h_n              (i_n h-part)
//   [768:1024)= Whh_n                (h_n)
// gi_pre = [x_in|m](131072x256) @ W2(256x768) + (bih + [bhh_r,bhh_z,0])
// gamma_h = exp(-relu( Delta(131072x128) @ Wdh^T + bdh ))

// ---- weight prep ---------------------------------------------------------
// Wc_sw  layout: [ks(8)][nt(64)][lane(64)][8]   (nt = g*16 + w)
// W2_sw  layout: [nt(48)][ks(8)][lane(64)][8]
// Wdh_sw layout: [nt(16)][ks(4)][lane(64)][8]
__global__ __launch_bounds__(256) void kw(
    const float* __restrict__ Wdh, const float* __restrict__ Wih,
    const float* __restrict__ Whh, const float* __restrict__ bih,
    const float* __restrict__ bhh,
    unsigned short* __restrict__ Wc, unsigned short* __restrict__ W2,
    unsigned short* __restrict__ Wd, float* __restrict__ b2){
  int i0 = blockIdx.x*256 + threadIdx.x;
  int stride = gridDim.x*256;
  for (int idx=i0; idx<262144; idx+=stride){
    int j = idx&7, l=(idx>>3)&63, nt=(idx>>9)&63, ks=idx>>15;
    int g=nt>>4, w=nt&15;
    int jh = w*16 + (l&15);
    int k = ks*32 + ((l>>4)<<3) + j;
    float v;
    if (g==0)      v = Wih[jh*512 + 128+k]       + Whh[jh*256 + k];
    else if (g==1) v = Wih[(256+jh)*512 + 128+k] + Whh[(256+jh)*256 + k];
    else if (g==2) v = Wih[(512+jh)*512 + 128+k];
    else           v = Whh[(512+jh)*256 + k];
    Wc[idx] = f2bf(v);
  }
  for (int idx=i0; idx<196608; idx+=stride){
    int j=idx&7, l=(idx>>3)&63, ks=(idx>>9)&7, nt=idx>>12;
    int n = nt*16 + (l&15);
    int k = ks*32 + ((l>>4)<<3) + j;
    float v = (k<128) ? Wih[n*512 + k] : Wih[n*512 + 256 + k]; // 384+(k-128)
    W2[idx] = f2bf(v);
  }
  for (int idx=i0; idx<32768; idx+=stride){
    int j=idx&7, l=(idx>>3)&63, ks=(idx>>9)&3, nt=idx>>11;
    int n = nt*16 + (l&15);
    int k = ks*32 + ((l>>4)<<3) + j;
    Wd[idx] = f2bf(Wdh[n*128 + k]);
  }
  for (int idx=i0; idx<768; idx+=stride)
    b2[idx] = bih[idx] + (idx<512 ? bhh[idx] : 0.f);
}

// ---- elementwise prep: Apre=[x_in|m] (T,B,256) bf16 ; Dt=(T,B,128) bf16 --
__global__ __launch_bounds__(256) void kprep(
    const float* __restrict__ X, const float* __restrict__ M,
    const float* __restrict__ D, const float* __restrict__ mu,
    const float* __restrict__ Xl, const float* __restrict__ Wdx,
    const float* __restrict__ bdx,
    unsigned short* __restrict__ Apre, unsigned short* __restrict__ Dt){
  int lane = threadIdx.x & 63;
  int wave = (blockIdx.x*256 + threadIdx.x) >> 6;
  int c0 = lane*2;
  float dg0 = Wdx[c0*128 + c0];
  float dg1 = Wdx[(c0+1)*128 + (c0+1)];
  float bx0 = bdx[c0], bx1 = bdx[c0+1];
  for (int r = wave; r < 131072; r += 4096){
    int t = r>>10, b = r&1023;
    size_t src = ((size_t)b*128 + t)*128 + c0;
    f32x2 x  = *(const f32x2*)(X+src);
    f32x2 m  = *(const f32x2*)(M+src);
    f32x2 d  = *(const f32x2*)(D+src);
    f32x2 xl = *(const f32x2*)(Xl+src);
    f32x2 mb = *(const f32x2*)(mu + b*128 + c0);
    float g0 = __expf(-fmaxf(0.f, d.x*dg0 + bx0));
    float g1 = __expf(-fmaxf(0.f, d.y*dg1 + bx1));
    float xh0 = g0*xl.x + (1.f-g0)*mb.x;
    float xh1 = g1*xl.y + (1.f-g1)*mb.y;
    float xi0 = m.x*x.x + (1.f-m.x)*xh0;
    float xi1 = m.y*x.y + (1.f-m.y)*xh1;
    size_t ar = (size_t)r*256;
    *(u16x2*)(Apre + ar + c0)        = u16x2{f2bf(xi0), f2bf(xi1)};
    *(u16x2*)(Apre + ar + 128 + c0)  = u16x2{f2bf(m.x), f2bf(m.y)};
    *(u16x2*)(Dt + (size_t)r*128 + c0) = u16x2{f2bf(d.x), f2bf(d.y)};
  }
}

// ---- batched activation GEMM: rows=131072, K=KS*32, N=NTOT*16 ------------
// wave handles 32 rows (2 M-tiles) x all N, in passes of PNT n-tiles.
// MODE 0: out = bf16(acc + bias)          (gi_pre)
// MODE 1: out = bf16(exp(-relu(acc+bias)))(gamma_h)
template<int KS, int NTOT, int PNT, int MODE>
__global__ __launch_bounds__(256) void gemm_act(
    const unsigned short* __restrict__ A, const unsigned short* __restrict__ Bw,
    const float* __restrict__ bias, unsigned short* __restrict__ out){
  const int N = NTOT*16;
  int lane = threadIdx.x & 63;
  int wid  = threadIdx.x >> 6;
  int gw   = blockIdx.x*4 + wid;
  size_t rb = (size_t)gw*32;
  int lr = lane&15, lk = (lane>>4)<<3, lq = (lane>>4)<<2;
  u16x8 a[2][KS];
  #pragma unroll
  for (int mt=0; mt<2; ++mt)
    #pragma unroll
    for (int ks=0; ks<KS; ++ks)
      a[mt][ks] = *(const u16x8*)&A[(rb + mt*16 + lr)*(KS*32) + ks*32 + lk];
  #pragma unroll
  for (int p=0; p<NTOT/PNT; ++p){
    f32x4 acc[2][PNT];
    #pragma unroll
    for (int mt=0; mt<2; ++mt)
      #pragma unroll
      for (int i=0; i<PNT; ++i) acc[mt][i] = f32x4{0.f,0.f,0.f,0.f};
    #pragma unroll
    for (int ks=0; ks<KS; ++ks){
      #pragma unroll
      for (int i=0; i<PNT; ++i){
        int nt = p*PNT + i;
        u16x8 b = *(const u16x8*)&Bw[((size_t)(nt*KS + ks)*64 + lane)*8];
        acc[0][i] = mfma16(a[0][ks], b, acc[0][i]);
        acc[1][i] = mfma16(a[1][ks], b, acc[1][i]);
      }
    }
    #pragma unroll
    for (int i=0; i<PNT; ++i){
      int nt = p*PNT + i; int col = nt*16 + lr;
      float bv = bias[col];
      #pragma unroll
      for (int mt=0; mt<2; ++mt){
        #pragma unroll
        for (int q=0; q<4; ++q){
          size_t row = rb + mt*16 + lq + q;
          float v = acc[mt][i][q] + bv;
          if (MODE==1) v = __expf(-fmaxf(0.f, v));
          out[row*N + col] = f2bf(v);
        }
      }
    }
  }
}

// ---- persistent sequential kernel ---------------------------------------
// 64 WGs x 1024 thr; WG owns 16 batch rows for all 128 steps.
// LDS: hf (f32 h state, in-place decayed), hsw (bf16 A-fragment-ordered h).
__global__ __launch_bounds__(1024) void seq(
    const unsigned short* __restrict__ Wc, const unsigned short* __restrict__ gamma,
    const unsigned short* __restrict__ gipre, const float* __restrict__ bhh,
    float* __restrict__ out){
  __shared__ float hf[4096];
  __shared__ unsigned short hsw[4096];
  const int tid = threadIdx.x;
  const int lane = tid & 63;
  const int w = tid >> 6;
  const int bbase = blockIdx.x * 16;
  for (int i = tid; i < 4096; i += 1024) hf[i] = 0.f;
  // decay-phase constants (thread owns 4 consecutive elements of hsw)
  const int e0 = tid*4;
  const int ksd = e0 >> 9;
  const int ld  = (e0 >> 3) & 63;
  const int j0  = e0 & 7;
  const int rowd = ld & 15;
  const int kb = ksd*32 + ((ld>>4)<<3) + j0;
  // epilogue constants
  const int jj = w*16 + (lane & 15);
  const float bn = bhh[512 + jj];
  const int rq0 = (lane >> 4) << 2;
  __syncthreads();
  for (int t = 0; t < 128; ++t){
    // ---- decay h, emit rep ----
    f32x4 h4 = *(const f32x4*)&hf[rowd*256 + kb];
    u16x4 g4 = *(const u16x4*)(gamma + ((size_t)t*1024 + bbase + rowd)*256 + kb);
    f32x4 hd;
    hd.x = h4.x * bf2f(g4[0]);
    hd.y = h4.y * bf2f(g4[1]);
    hd.z = h4.z * bf2f(g4[2]);
    hd.w = h4.w * bf2f(g4[3]);
    *(f32x4*)(out + ((size_t)(bbase+rowd)*128 + t)*256 + kb) = hd;
    *(f32x4*)&hf[rowd*256 + kb] = hd;
    *(u16x4*)&hsw[(ksd*64 + ld)*8 + j0] =
        u16x4{f2bf(hd.x), f2bf(hd.y), f2bf(hd.z), f2bf(hd.w)};
    __syncthreads();
    // ---- S = h_dec @ Wc (each wave: 4 n-tiles = its 16 h-dims x 4 groups) --
    u16x8 a[8];
    #pragma unroll
    for (int ks=0; ks<8; ++ks) a[ks] = *(const u16x8*)&hsw[(ks*64 + lane)*8];
    f32x4 acc0={0.f,0.f,0.f,0.f}, acc1={0.f,0.f,0.f,0.f};
    f32x4 acc2={0.f,0.f,0.f,0.f}, acc3={0.f,0.f,0.f,0.f};
    #pragma unroll
    for (int ks=0; ks<8; ++ks){
      u16x8 b0 = *(const u16x8*)&Wc[((size_t)(ks*64 +  0 + w)*64 + lane)*8];
      u16x8 b1 = *(const u16x8*)&Wc[((size_t)(ks*64 + 16 + w)*64 + lane)*8];
      u16x8 b2 = *(const u16x8*)&Wc[((size_t)(ks*64 + 32 + w)*64 + lane)*8];
      u16x8 b3 = *(const u16x8*)&Wc[((size_t)(ks*64 + 48 + w)*64 + lane)*8];
      acc0 = mfma16(a[ks], b0, acc0);
      acc1 = mfma16(a[ks], b1, acc1);
      acc2 = mfma16(a[ks], b2, acc2);
      acc3 = mfma16(a[ks], b3, acc3);
    }
    // ---- gates + h update ----
    const unsigned short* gp = gipre + ((size_t)t*1024 + bbase)*768;
    #pragma unroll
    for (int q=0; q<4; ++q){
      int r = rq0 + q;
      float gr = bf2f(gp[(size_t)r*768 + jj]);
      float gz = bf2f(gp[(size_t)r*768 + 256 + jj]);
      float gn = bf2f(gp[(size_t)r*768 + 512 + jj]);
      float hdv = hf[r*256 + jj];
      float rr = sigm(gr + acc0[q]);
      float zz = sigm(gz + acc1[q]);
      float nv = tanh_f(gn + acc2[q] + rr*(acc3[q] + bn));
      float hn = (1.f-zz)*nv + zz*hdv;
      hf[r*256 + jj] = hn;
      if (t == 127) out[(size_t)33554432 + (size_t)(bbase+r)*256 + jj] = hn;
    }
    __syncthreads();
  }
}

// ---- host glue -----------------------------------------------------------
extern "C" void kernel_launch(void* const* d_in, const int* in_sizes, int n_in,
                              void* d_out, int out_size, void* d_ws, size_t ws_size,
                              hipStream_t stream){
  (void)in_sizes; (void)n_in; (void)out_size; (void)ws_size;
  const float* X   = (const float*)d_in[0];
  const float* M   = (const float*)d_in[1];
  const float* D   = (const float*)d_in[2];
  const float* mu  = (const float*)d_in[3];
  const float* Xl  = (const float*)d_in[4];
  const float* Wdh = (const float*)d_in[5];
  const float* bdh = (const float*)d_in[6];
  const float* Wdx = (const float*)d_in[7];
  const float* bdx = (const float*)d_in[8];
  const float* Wih = (const float*)d_in[9];
  const float* Whh = (const float*)d_in[10];
  const float* bih = (const float*)d_in[11];
  const float* bhh = (const float*)d_in[12];
  float* out = (float*)d_out;
  char* ws = (char*)d_ws;

  // workspace layout
  unsigned short* gipre = (unsigned short*)ws;                      // 201326592 B
  unsigned short* gamma = (unsigned short*)(ws + 201326592);        //  67108864 B
  unsigned short* Wcsw  = (unsigned short*)(ws + 268435456);        //    524288 B
  unsigned short* W2sw  = (unsigned short*)(ws + 268959744);        //    393216 B
  unsigned short* Wdsw  = (unsigned short*)(ws + 269352960);        //     65536 B
  float*          b2    = (float*)        (ws + 269418496);         //      3072 B
  // Apre (67.1MB) + Dt (33.6MB) staged inside d_out (135.3MB): both are fully
  // consumed by the GEMMs below BEFORE seq writes the real outputs.
  unsigned short* Apre = (unsigned short*)d_out;
  unsigned short* Dt   = (unsigned short*)((char*)d_out + 67108864);

  kw<<<256, 256, 0, stream>>>(Wdh, Wih, Whh, bih, bhh, Wcsw, W2sw, Wdsw, b2);
  kprep<<<1024, 256, 0, stream>>>(X, M, D, mu, Xl, Wdx, bdx, Apre, Dt);
  gemm_act<4,16,8,1><<<1024, 256, 0, stream>>>(Dt, Wdsw, bdh, gamma);
  gemm_act<8,48,8,0><<<1024, 256, 0, stream>>>(Apre, W2sw, b2, gipre);
  seq<<<64, 1024, 0, stream>>>(Wcsw, gamma, gipre, bhh, out);
}